// Round 23
// baseline (166.780 us; speedup 1.0000x reference)
//
#include <hip/hip_runtime.h>

#define EMBED   1024
#define HEADS   16
#define HDIM    64
#define SEQ     2048
#define BATCH   4
#define QKV_LD  3072

typedef __attribute__((ext_vector_type(8))) short short8v;
typedef __attribute__((ext_vector_type(4))) float floatx4;
typedef __attribute__((ext_vector_type(4))) unsigned int uint4v;

// log2(e)/8 : folded into Q so S comes out in base-2 units
#define QSCALE 0.18033688011112042f

__device__ __forceinline__ unsigned short f2bf(float f) {
    unsigned int u = __builtin_bit_cast(unsigned int, f);
    u += 0x7FFFu + ((u >> 16) & 1u);
    return (unsigned short)(u >> 16);
}

__device__ __forceinline__ float fast_exp2(float x) {
    float r;
    asm("v_exp_f32 %0, %1" : "=v"(r) : "v"(x));
    return r;
}
__device__ __forceinline__ unsigned int cvt_pk_bf16(float lo, float hi) {
    unsigned int r;
    asm("v_cvt_pk_bf16_f32 %0, %1, %2" : "=v"(r) : "v"(lo), "v"(hi));
    return r;
}
// async global->LDS, 16B per lane; LDS dest = wave-uniform base + lane*16
__device__ __forceinline__ void gload_lds16(const unsigned short* g, unsigned short* l) {
    __builtin_amdgcn_global_load_lds(
        (const __attribute__((address_space(1))) unsigned int*)g,
        (__attribute__((address_space(3))) unsigned int*)l, 16, 0, 0);
}

// ---------------------------------------------------------------------------
// Union prep kernel: one launch = cast x (8192 blocks) + transpose W_qkv
// (768) + transpose W_proj (256).  Byte-identical outputs to the separate
// kernels (round 22: -3.4 us from removing two launch/tail boundaries).
// ---------------------------------------------------------------------------
__global__ __launch_bounds__(256) void prep_kernel(const float* __restrict__ x,
                                                   unsigned short* __restrict__ x_b,
                                                   const float* __restrict__ Wq,
                                                   unsigned short* __restrict__ wqT,
                                                   const float* __restrict__ Wp,
                                                   unsigned short* __restrict__ wpT) {
    __shared__ float T[64][65];
    const int bid = blockIdx.x;
    const int t = threadIdx.x;

    if (bid < 8192) {
        int i = bid * 256 + t;
        float4 v = ((const float4*)x)[i];
        unsigned short o[4] = { f2bf(v.x), f2bf(v.y), f2bf(v.z), f2bf(v.w) };
        ((uint2*)x_b)[i] = *(uint2*)o;
        return;
    }

    const float* in;
    unsigned short* out;
    int K, N, k0, n0;
    if (bid < 8192 + 768) {
        int flat = bid - 8192;
        in = Wq; out = wqT; K = EMBED; N = QKV_LD;
        n0 = (flat % 48) * 64; k0 = (flat / 48) * 64;
    } else {
        int flat = bid - 8960;
        in = Wp; out = wpT; K = EMBED; N = EMBED;
        n0 = (flat % 16) * 64; k0 = (flat / 16) * 64;
    }

    #pragma unroll
    for (int i = 0; i < 4; ++i) {
        int s = i * 256 + t;
        int k = s >> 4, c4 = s & 15;
        float4 v = *(const float4*)(in + (size_t)(k0 + k) * N + n0 + c4 * 4);
        T[k][c4*4+0] = v.x; T[k][c4*4+1] = v.y; T[k][c4*4+2] = v.z; T[k][c4*4+3] = v.w;
    }
    __syncthreads();
    const int n = t >> 2, kc = (t & 3) * 16;
    unsigned short tmp[16];
    #pragma unroll
    for (int j = 0; j < 16; ++j) tmp[j] = f2bf(T[kc + j][n]);
    *(short8v*)(out + (size_t)(n0 + n) * K + k0 + kc)     = *(short8v*)&tmp[0];
    *(short8v*)(out + (size_t)(n0 + n) * K + k0 + kc + 8) = *(short8v*)&tmp[8];
}

// ---------------------------------------------------------------------------
// bf16 MFMA GEMM, 256x128 tile, BK=64, 512 threads / 8 waves (4M x 2N).
// Round-12 pipeline (3 LDS K-tile buffers, 2-tile-deep prefetch, counted
// vmcnt(6)) + round-21 M-fast XCD order (A panels L2-pinned, B streamed
// once).  Round 23: the mid-phase s_barrier is REMOVED — it had no
// correctness role (buffer safety is the top vmcnt+barrier: read buf cur,
// stage buf cur+2) and cost one extra 8-wave sync per K-tile.  One barrier
// + one 32-MFMA cluster + 16 ds_read_b128 per iteration.
// FUSE_VT: V-third blocks (col0 >= 2048) write their C tile transposed+
// permuted straight to vt via a d-major LDS bounce (vectorized).
// Permutation (attention PV B-frag): position (d, cp, j) holds
// V[kv=(c>>2)*32+16*(j>=4)+(c&3)*4+(j&3)][d], c = cp ^ (d&7).
// ---------------------------------------------------------------------------
template<bool OUT_BF16, bool SCALE_Q, bool FUSE_VT>
__global__ __launch_bounds__(512) void gemm_bf16(const unsigned short* __restrict__ A,
                                                 const unsigned short* __restrict__ BT,
                                                 const float* __restrict__ bias,
                                                 void* __restrict__ Cout,
                                                 unsigned short* __restrict__ vtout,
                                                 int M, int N, int K) {
    __shared__ __align__(16) unsigned short As[3][256 * 64];   // 96 KB
    __shared__ __align__(16) unsigned short Bs[3][128 * 64];   // 48 KB
    const int tid = threadIdx.x;
    const int lane = tid & 63;
    const int w = tid >> 6;            // 0..7
    const int wm = w >> 1, wn = w & 1; // 4 x 2 wave grid
    const int lq = lane & 15, lg = lane >> 4;
    const int lq7 = lq & 7;

    // M-fast XCD remap (M/256 == 32 M-panels, 4 per XCD)
    const int xcd = blockIdx.x & 7;
    const int loc = blockIdx.x >> 3;
    const int by = xcd * 4 + (loc & 3);
    const int bx = loc >> 2;
    const int row0 = by * 256, col0 = bx * 128;

    int arow[4], acol[4], brow[2], bcol[2];
    #pragma unroll
    for (int i = 0; i < 4; ++i) {
        int ch = w*256 + i*64 + lane;
        arow[i] = ch >> 3;
        acol[i] = ((lane & 7) ^ (arow[i] & 7)) * 8;
    }
    #pragma unroll
    for (int i = 0; i < 2; ++i) {
        int ch = w*128 + i*64 + lane;
        brow[i] = ch >> 3;
        bcol[i] = ((lane & 7) ^ (brow[i] & 7)) * 8;
    }

    const int fbA0 = (wm*64 + lq) * 64 + ((0 + lg) ^ lq7) * 8;
    const int fbA1 = (wm*64 + lq) * 64 + ((4 + lg) ^ lq7) * 8;
    const int fbB0 = (wn*64 + lq) * 64 + ((0 + lg) ^ lq7) * 8;
    const int fbB1 = (wn*64 + lq) * 64 + ((4 + lg) ^ lq7) * 8;

    floatx4 acc[4][4];
    #pragma unroll
    for (int i = 0; i < 4; ++i)
        #pragma unroll
        for (int j = 0; j < 4; ++j)
            acc[i][j] = (floatx4){0.f, 0.f, 0.f, 0.f};

#define GSTAGE_H1(KK_, BUF_) do {                                                              \
        gload_lds16(A  + (size_t)(row0 + arow[0]) * K + (KK_) + acol[0], &As[BUF_][(w*256 +   0) * 8]); \
        gload_lds16(A  + (size_t)(row0 + arow[1]) * K + (KK_) + acol[1], &As[BUF_][(w*256 +  64) * 8]); \
        gload_lds16(BT + (size_t)(col0 + brow[0]) * K + (KK_) + bcol[0], &Bs[BUF_][(w*128 +   0) * 8]); \
    } while (0)
#define GSTAGE_H2(KK_, BUF_) do {                                                              \
        gload_lds16(A  + (size_t)(row0 + arow[2]) * K + (KK_) + acol[2], &As[BUF_][(w*256 + 128) * 8]); \
        gload_lds16(A  + (size_t)(row0 + arow[3]) * K + (KK_) + acol[3], &As[BUF_][(w*256 + 192) * 8]); \
        gload_lds16(BT + (size_t)(col0 + brow[1]) * K + (KK_) + bcol[1], &Bs[BUF_][(w*128 +  64) * 8]); \
    } while (0)

    const int NKT = K >> 6;
    GSTAGE_H1(0, 0);  GSTAGE_H2(0, 0);
    GSTAGE_H1(64, 1); GSTAGE_H2(64, 1);

    int cur = 0;
    for (int kt = 0; kt < NKT; ++kt) {
        if (kt == NKT - 1) asm volatile("s_waitcnt vmcnt(0)" ::: "memory");
        else               asm volatile("s_waitcnt vmcnt(6)" ::: "memory");
        __builtin_amdgcn_s_barrier();
        __builtin_amdgcn_sched_barrier(0);

        int sb = cur + 2; if (sb >= 3) sb -= 3;
        const int kk2 = (kt + 2) << 6;
        const bool do_stage = (kt + 2 < NKT);

        // single merged phase: 16 ds_read_b128 + 6 stage issues + 32 MFMA
        short8v af0[4], bf0[4], af1[4], bf1[4];
        #pragma unroll
        for (int mi = 0; mi < 4; ++mi) af0[mi] = *(const short8v*)(&As[cur][fbA0 + mi*1024]);
        #pragma unroll
        for (int ni = 0; ni < 4; ++ni) bf0[ni] = *(const short8v*)(&Bs[cur][fbB0 + ni*1024]);
        if (do_stage) GSTAGE_H1(kk2, sb);
        #pragma unroll
        for (int mi = 0; mi < 4; ++mi) af1[mi] = *(const short8v*)(&As[cur][fbA1 + mi*1024]);
        #pragma unroll
        for (int ni = 0; ni < 4; ++ni) bf1[ni] = *(const short8v*)(&Bs[cur][fbB1 + ni*1024]);
        if (do_stage) GSTAGE_H2(kk2, sb);

        __builtin_amdgcn_s_setprio(1);
        #pragma unroll
        for (int mi = 0; mi < 4; ++mi)
            #pragma unroll
            for (int ni = 0; ni < 4; ++ni)
                acc[mi][ni] = __builtin_amdgcn_mfma_f32_16x16x32_bf16(af0[mi], bf0[ni], acc[mi][ni], 0, 0, 0);
        #pragma unroll
        for (int mi = 0; mi < 4; ++mi)
            #pragma unroll
            for (int ni = 0; ni < 4; ++ni)
                acc[mi][ni] = __builtin_amdgcn_mfma_f32_16x16x32_bf16(af1[mi], bf1[ni], acc[mi][ni], 0, 0, 0);
        __builtin_amdgcn_s_setprio(0);

        cur = (cur == 2) ? 0 : cur + 1;
    }
#undef GSTAGE_H1
#undef GSTAGE_H2

    if constexpr (FUSE_VT) {
        if (col0 >= 2*EMBED) {
            // ---- V third: d-major LDS bounce, all-vector traffic ----
            unsigned short* Tl = &As[0][0];     // need 128*264*2 = 67.6 KB <= 96 KB
            const int TR = 264;                 // halfword stride per d-column (+8 pad)
            __syncthreads();                    // all waves done reading As
            #pragma unroll
            for (int ni = 0; ni < 4; ++ni) {
                int cl = wn*64 + ni*16 + lq;    // 0..127 (d within block)
                float bv = bias[col0 + cl];
                #pragma unroll
                for (int mi = 0; mi < 4; ++mi) {
                    uint2 uu;
                    uu.x = cvt_pk_bf16(acc[mi][ni][0] + bv, acc[mi][ni][1] + bv);
                    uu.y = cvt_pk_bf16(acc[mi][ni][2] + bv, acc[mi][ni][3] + bv);
                    *(uint2*)(Tl + cl*TR + wm*64 + mi*16 + lg*4) = uu;
                }
            }
            __syncthreads();
            const int b_ = row0 >> 11;              // batch
            const int n0 = row0 & 2047;             // kv base within sequence
            const int h0 = (col0 - 2*EMBED) >> 6;   // first head in this block
            #pragma unroll
            for (int i = 0; i < 8; ++i) {
                int s = i * 512 + tid;              // 0..4095
                int cp = s & 7, t = (s >> 3) & 3, d = (s >> 5) & 63, hh = s >> 11;
                int c = cp ^ (d & 7);
                int base = (c >> 2) * 32 + (c & 3) * 4;
                int cl = hh*64 + d;
                uint2 lo = *(const uint2*)(Tl + cl*TR + t*64 + base);
                uint2 hi = *(const uint2*)(Tl + cl*TR + t*64 + base + 16);
                uint4v tv = (uint4v){ lo.x, lo.y, hi.x, hi.y };
                int bh = b_ * 16 + h0 + hh;
                *(short8v*)(vtout + ((size_t)bh * HDIM + d) * SEQ + n0 + t*64 + cp*8) =
                    __builtin_bit_cast(short8v, tv);
            }
            return;
        }
    }

    #pragma unroll
    for (int mi = 0; mi < 4; ++mi) {
        #pragma unroll
        for (int ni = 0; ni < 4; ++ni) {
            int col = col0 + wn*64 + ni*16 + lq;
            float bv = bias[col];
            #pragma unroll
            for (int r = 0; r < 4; ++r) {
                int row = row0 + wm*64 + mi*16 + lg*4 + r;
                float v = acc[mi][ni][r] + bv;
                if constexpr (SCALE_Q) { if (col < EMBED) v *= QSCALE; }
                if constexpr (OUT_BF16)
                    ((unsigned short*)Cout)[(size_t)row * N + col] = f2bf(v);
                else
                    ((float*)Cout)[(size_t)row * N + col] = v;
            }
        }
    }
}

// ---------------------------------------------------------------------------
// MFMA flash attention (final form, ~72 us, issue-saturated: MfmaUtil +
// VALUBusy ~ 88%): 8 waves / 512 threads, QBLK=256, swapped QK^T,
// pi-permuted PV, no-max softmax, ones-MFMA lsum, XCD remap, paired 2x2
// K/V buffers (64 KB), one vmcnt(0)+s_barrier per 2-tile epoch,
// wave-staggered tile order.
// ---------------------------------------------------------------------------
__global__ __launch_bounds__(512) void attn_mfma(const unsigned short* __restrict__ qkvb,
                                                 const unsigned short* __restrict__ vt,
                                                 unsigned short* __restrict__ attout) {
    const int flat = blockIdx.x;          // 0..511
    const int idx = flat >> 3;            // 0..63
    const int bh = (flat & 7) * 8 + (idx >> 3);
    const int qb = idx & 7;
    const int b = bh >> 4, h = bh & 15;
    const int tid = threadIdx.x;
    const int lane = tid & 63;
    const int w = tid >> 6;               // 0..7
    const int lq = lane & 15, lg = lane >> 4;
    const int rb = lq & 7;

    __shared__ __align__(16) unsigned short Ks[2][2][64 * 64];   // 32 KB
    __shared__ __align__(16) unsigned short Vs[2][2][64 * 64];   // 32 KB

    short8v qf[2][2];
    const unsigned short* qbase = qkvb + (size_t)(b*SEQ + qb*256 + w*32) * QKV_LD + h*HDIM;
    #pragma unroll
    for (int m = 0; m < 2; ++m)
        #pragma unroll
        for (int ks = 0; ks < 2; ++ks)
            qf[m][ks] = *(const short8v*)(qbase + (size_t)(m*16 + lq) * QKV_LD + ks*32 + lg*8);

    floatx4 o[2][4];
    #pragma unroll
    for (int m = 0; m < 2; ++m)
        #pragma unroll
        for (int dt = 0; dt < 4; ++dt)
            o[m][dt] = (floatx4){0.f, 0.f, 0.f, 0.f};
    floatx4 lacc[2];
    lacc[0] = (floatx4){0.f, 0.f, 0.f, 0.f};
    lacc[1] = (floatx4){0.f, 0.f, 0.f, 0.f};

    const uint4v onesu = (uint4v){0x3F803F80u, 0x3F803F80u, 0x3F803F80u, 0x3F803F80u};
    const short8v onesf = __builtin_bit_cast(short8v, onesu);

    const unsigned short* kbase = qkvb + (size_t)(b*SEQ) * QKV_LD + EMBED + h*HDIM;
    const unsigned short* vbase = vt + (size_t)bh * HDIM * SEQ;

    const int r0 = tid >> 3;
    const int ck0 = (tid & 7) ^ (r0 & 7);
    const int cv0 = tid & 7;

    const int cA = (lg ^ rb) * 8, cB = ((lg ^ rb) ^ 4) * 8;
    const int fbA = lq * 64 + cA, fbB = lq * 64 + cB;
    const int sw0 = w & 1;                 // this wave's first sub-tile

#define STAGE(T_, PP_, SS_) do {                                                   \
        const unsigned short* kb_ = kbase + (size_t)(T_) * 64 * QKV_LD;            \
        const unsigned short* vb_ = vbase + (T_) * 64;                             \
        gload_lds16(kb_ + (size_t)r0 * QKV_LD + ck0*8, &Ks[PP_][SS_][w*512]);      \
        gload_lds16(vb_ + (size_t)r0 * SEQ + cv0*8,    &Vs[PP_][SS_][w*512]);      \
    } while (0)

#define ACOMP(PP_, SS_) do {                                                                   \
        const unsigned short* K0 = &Ks[PP_][SS_][fbA];                                         \
        const unsigned short* K1 = &Ks[PP_][SS_][fbB];                                         \
        const unsigned short* V0 = &Vs[PP_][SS_][fbA];                                         \
        const unsigned short* V1 = &Vs[PP_][SS_][fbB];                                         \
        floatx4 sacc[2][4];                                                                    \
        _Pragma("unroll")                                                                      \
        for (int n = 0; n < 4; ++n) {                                                          \
            short8v kf0 = *(const short8v*)(K0 + n * 1024);                                    \
            short8v kf1 = *(const short8v*)(K1 + n * 1024);                                    \
            __builtin_amdgcn_s_setprio(1);                                                     \
            _Pragma("unroll")                                                                  \
            for (int m = 0; m < 2; ++m) {                                                      \
                floatx4 z = (floatx4){0.f, 0.f, 0.f, 0.f};                                     \
                z = __builtin_amdgcn_mfma_f32_16x16x32_bf16(kf0, qf[m][0], z, 0, 0, 0);        \
                sacc[m][n] = __builtin_amdgcn_mfma_f32_16x16x32_bf16(kf1, qf[m][1], z, 0, 0, 0); \
            }                                                                                  \
            __builtin_amdgcn_s_setprio(0);                                                     \
        }                                                                                      \
        uint4v afu[2][2];                                                                      \
        _Pragma("unroll")                                                                      \
        for (int m = 0; m < 2; ++m) {                                                          \
            unsigned int pk[4][2];                                                             \
            _Pragma("unroll")                                                                  \
            for (int n = 0; n < 4; ++n) {                                                      \
                float p0 = fast_exp2(sacc[m][n][0]);                                           \
                float p1 = fast_exp2(sacc[m][n][1]);                                           \
                float p2 = fast_exp2(sacc[m][n][2]);                                           \
                float p3 = fast_exp2(sacc[m][n][3]);                                           \
                pk[n][0] = cvt_pk_bf16(p0, p1);                                                \
                pk[n][1] = cvt_pk_bf16(p2, p3);                                                \
            }                                                                                  \
            afu[m][0] = (uint4v){ pk[0][0], pk[0][1], pk[1][0], pk[1][1] };                    \
            afu[m][1] = (uint4v){ pk[2][0], pk[2][1], pk[3][0], pk[3][1] };                    \
        }                                                                                      \
        __builtin_amdgcn_s_setprio(1);                                                         \
        _Pragma("unroll")                                                                      \
        for (int m = 0; m < 2; ++m) {                                                          \
            lacc[m] = __builtin_amdgcn_mfma_f32_16x16x32_bf16(                                 \
                __builtin_bit_cast(short8v, afu[m][0]), onesf, lacc[m], 0, 0, 0);              \
            lacc[m] = __builtin_amdgcn_mfma_f32_16x16x32_bf16(                                 \
                __builtin_bit_cast(short8v, afu[m][1]), onesf, lacc[m], 0, 0, 0);              \
        }                                                                                      \
        __builtin_amdgcn_s_setprio(0);                                                         \
        _Pragma("unroll")                                                                      \
        for (int dt = 0; dt < 4; ++dt) {                                                       \
            short8v vf0 = *(const short8v*)(V0 + dt * 1024);                                   \
            short8v vf1 = *(const short8v*)(V1 + dt * 1024);                                   \
            __builtin_amdgcn_s_setprio(1);                                                     \
            _Pragma("unroll")                                                                  \
            for (int m = 0; m < 2; ++m) {                                                      \
                o[m][dt] = __builtin_amdgcn_mfma_f32_16x16x32_bf16(                            \
                    __builtin_bit_cast(short8v, afu[m][0]), vf0, o[m][dt], 0, 0, 0);           \
                o[m][dt] = __builtin_amdgcn_mfma_f32_16x16x32_bf16(                            \
                    __builtin_bit_cast(short8v, afu[m][1]), vf1, o[m][dt], 0, 0, 0);           \
            }                                                                                  \
            __builtin_amdgcn_s_setprio(0);                                                     \
        }                                                                                      \
    } while (0)

    const int NT = SEQ / 64;   // 32
    STAGE(0, 0, 0);
    STAGE(1, 0, 1);

    for (int kt = 0; kt < NT; kt += 2) {
        const int p = (kt >> 1) & 1;
        asm volatile("s_waitcnt vmcnt(0)" ::: "memory");
        __builtin_amdgcn_s_barrier();
        __builtin_amdgcn_sched_barrier(0);

        if (kt + 2 < NT) {
            STAGE(kt + 2, p ^ 1, 0);
            STAGE(kt + 3, p ^ 1, 1);
        }

        ACOMP(p, sw0);
        ACOMP(p, sw0 ^ 1);
    }
#undef ACOMP
#undef STAGE

    // ---- epilogue: lacc rows (lg*4+r) match o rows exactly — no shuffles ----
    #pragma unroll
    for (int m = 0; m < 2; ++m) {
        #pragma unroll
        for (int dt = 0; dt < 4; ++dt) {
            #pragma unroll
            for (int r = 0; r < 4; ++r) {
                float v = o[m][dt][r] / lacc[m][r];
                int row = qb*256 + w*32 + m*16 + lg*4 + r;
                int col = h*HDIM + dt*16 + lq;
                attout[(size_t)(b*SEQ + row) * EMBED + col] = f2bf(v);
            }
        }
    }
}

// ---------------------------------------------------------------------------
extern "C" void kernel_launch(void* const* d_in, const int* in_sizes, int n_in,
                              void* d_out, int out_size, void* d_ws, size_t ws_size,
                              hipStream_t stream) {
    const float* x      = (const float*)d_in[0];
    const float* W_qkv  = (const float*)d_in[1];
    const float* b_qkv  = (const float*)d_in[2];
    const float* W_proj = (const float*)d_in[3];
    const float* b_proj = (const float*)d_in[4];
    float* out = (float*)d_out;

    const int M = BATCH * SEQ;   // 8192

    char* ws = (char*)d_ws;
    unsigned short* x_b    = (unsigned short*)(ws);                 // 16 MB
    unsigned short* wqkvT  = (unsigned short*)(ws + 16777216);      // 6 MB
    unsigned short* wprojT = (unsigned short*)(ws + 23068672);      // 2 MB
    unsigned short* qkv_b  = (unsigned short*)(ws + 25165824);      // 48 MB
    unsigned short* vt_b   = (unsigned short*)(ws + 75497472);      // 16 MB
    unsigned short* att_b  = (unsigned short*)(ws + 92274688);      // 16 MB

    // one fused prep launch: cast(8192) + tqkv(768) + tproj(256) = 9216 blocks
    prep_kernel<<<dim3(9216), 256, 0, stream>>>(x, x_b, W_qkv, wqkvT, W_proj, wprojT);

    // QKV: grid 32*24 = 768 blocks; V third written directly to vt_b
    gemm_bf16<true, true, true><<<dim3(768), 512, 0, stream>>>(
        x_b, wqkvT, b_qkv, qkv_b, vt_b, M, QKV_LD, EMBED);

    // attn: grid 512 (QBLK=256)
    attn_mfma<<<dim3(512), dim3(512), 0, stream>>>(qkv_b, vt_b, att_b);

    // proj: grid 32*8 = 256 blocks
    gemm_bf16<false, false, false><<<dim3(256), 512, 0, stream>>>(
        att_b, wprojT, b_proj, out, nullptr, M, EMBED, EMBED);
}

// Round 24
// 157.730 us; speedup vs baseline: 1.0574x; 1.0574x over previous
//
#include <hip/hip_runtime.h>

#define EMBED   1024
#define HEADS   16
#define HDIM    64
#define SEQ     2048
#define BATCH   4
#define QKV_LD  3072

typedef __attribute__((ext_vector_type(8))) short short8v;
typedef __attribute__((ext_vector_type(4))) float floatx4;
typedef __attribute__((ext_vector_type(4))) unsigned int uint4v;

// log2(e)/8 : folded into Q so S comes out in base-2 units
#define QSCALE 0.18033688011112042f

__device__ __forceinline__ unsigned short f2bf(float f) {
    unsigned int u = __builtin_bit_cast(unsigned int, f);
    u += 0x7FFFu + ((u >> 16) & 1u);
    return (unsigned short)(u >> 16);
}

__device__ __forceinline__ float fast_exp2(float x) {
    float r;
    asm("v_exp_f32 %0, %1" : "=v"(r) : "v"(x));
    return r;
}
__device__ __forceinline__ unsigned int cvt_pk_bf16(float lo, float hi) {
    unsigned int r;
    asm("v_cvt_pk_bf16_f32 %0, %1, %2" : "=v"(r) : "v"(lo), "v"(hi));
    return r;
}
// async global->LDS, 16B per lane; LDS dest = wave-uniform base + lane*16
__device__ __forceinline__ void gload_lds16(const unsigned short* g, unsigned short* l) {
    __builtin_amdgcn_global_load_lds(
        (const __attribute__((address_space(1))) unsigned int*)g,
        (__attribute__((address_space(3))) unsigned int*)l, 16, 0, 0);
}

// ---------------------------------------------------------------------------
// Union prep kernel: one launch = cast x (8192 blocks) + transpose W_qkv
// (768) + transpose W_proj (256).  Byte-identical outputs to the separate
// kernels (round 22: -3.4 us from removing two launch/tail boundaries).
// ---------------------------------------------------------------------------
__global__ __launch_bounds__(256) void prep_kernel(const float* __restrict__ x,
                                                   unsigned short* __restrict__ x_b,
                                                   const float* __restrict__ Wq,
                                                   unsigned short* __restrict__ wqT,
                                                   const float* __restrict__ Wp,
                                                   unsigned short* __restrict__ wpT) {
    __shared__ float T[64][65];
    const int bid = blockIdx.x;
    const int t = threadIdx.x;

    if (bid < 8192) {
        int i = bid * 256 + t;
        float4 v = ((const float4*)x)[i];
        unsigned short o[4] = { f2bf(v.x), f2bf(v.y), f2bf(v.z), f2bf(v.w) };
        ((uint2*)x_b)[i] = *(uint2*)o;
        return;
    }

    const float* in;
    unsigned short* out;
    int K, N, k0, n0;
    if (bid < 8192 + 768) {
        int flat = bid - 8192;
        in = Wq; out = wqT; K = EMBED; N = QKV_LD;
        n0 = (flat % 48) * 64; k0 = (flat / 48) * 64;
    } else {
        int flat = bid - 8960;
        in = Wp; out = wpT; K = EMBED; N = EMBED;
        n0 = (flat % 16) * 64; k0 = (flat / 16) * 64;
    }

    #pragma unroll
    for (int i = 0; i < 4; ++i) {
        int s = i * 256 + t;
        int k = s >> 4, c4 = s & 15;
        float4 v = *(const float4*)(in + (size_t)(k0 + k) * N + n0 + c4 * 4);
        T[k][c4*4+0] = v.x; T[k][c4*4+1] = v.y; T[k][c4*4+2] = v.z; T[k][c4*4+3] = v.w;
    }
    __syncthreads();
    const int n = t >> 2, kc = (t & 3) * 16;
    unsigned short tmp[16];
    #pragma unroll
    for (int j = 0; j < 16; ++j) tmp[j] = f2bf(T[kc + j][n]);
    *(short8v*)(out + (size_t)(n0 + n) * K + k0 + kc)     = *(short8v*)&tmp[0];
    *(short8v*)(out + (size_t)(n0 + n) * K + k0 + kc + 8) = *(short8v*)&tmp[8];
}

// ---------------------------------------------------------------------------
// bf16 MFMA GEMM, 256x128 tile, BK=64, 512 threads / 8 waves (4M x 2N).
// Round-12 pipeline: 3 LDS K-tile buffers, 2-tile-deep prefetch, counted
// s_waitcnt vmcnt(6), TWO 16-MFMA phases per iter with a mid-phase barrier
// (round 23 proved removing it regresses: merged phase doubles live
// fragment state and serializes 16 ds_reads ahead of the MFMA cluster).
// Round-21 M-fast XCD order: 32 co-resident blocks/XCD = 4 M-panels
// (A 2 MB L2-pinned) x 8 N-panels (B 2 MB streamed once) = 4 MB L2 fit.
// FUSE_VT: V-third blocks (col0 >= 2048) write their C tile transposed+
// permuted straight to vt via a d-major LDS bounce (vectorized).
// Permutation (attention PV B-frag): position (d, cp, j) holds
// V[kv=(c>>2)*32+16*(j>=4)+(c&3)*4+(j&3)][d], c = cp ^ (d&7).
// ---------------------------------------------------------------------------
template<bool OUT_BF16, bool SCALE_Q, bool FUSE_VT>
__global__ __launch_bounds__(512) void gemm_bf16(const unsigned short* __restrict__ A,
                                                 const unsigned short* __restrict__ BT,
                                                 const float* __restrict__ bias,
                                                 void* __restrict__ Cout,
                                                 unsigned short* __restrict__ vtout,
                                                 int M, int N, int K) {
    __shared__ __align__(16) unsigned short As[3][256 * 64];   // 96 KB
    __shared__ __align__(16) unsigned short Bs[3][128 * 64];   // 48 KB
    const int tid = threadIdx.x;
    const int lane = tid & 63;
    const int w = tid >> 6;            // 0..7
    const int wm = w >> 1, wn = w & 1; // 4 x 2 wave grid
    const int lq = lane & 15, lg = lane >> 4;
    const int lq7 = lq & 7;

    // M-fast XCD remap (M/256 == 32 M-panels, 4 per XCD)
    const int xcd = blockIdx.x & 7;
    const int loc = blockIdx.x >> 3;
    const int by = xcd * 4 + (loc & 3);
    const int bx = loc >> 2;
    const int row0 = by * 256, col0 = bx * 128;

    int arow[4], acol[4], brow[2], bcol[2];
    #pragma unroll
    for (int i = 0; i < 4; ++i) {
        int ch = w*256 + i*64 + lane;
        arow[i] = ch >> 3;
        acol[i] = ((lane & 7) ^ (arow[i] & 7)) * 8;
    }
    #pragma unroll
    for (int i = 0; i < 2; ++i) {
        int ch = w*128 + i*64 + lane;
        brow[i] = ch >> 3;
        bcol[i] = ((lane & 7) ^ (brow[i] & 7)) * 8;
    }

    const int fbA0 = (wm*64 + lq) * 64 + ((0 + lg) ^ lq7) * 8;
    const int fbA1 = (wm*64 + lq) * 64 + ((4 + lg) ^ lq7) * 8;
    const int fbB0 = (wn*64 + lq) * 64 + ((0 + lg) ^ lq7) * 8;
    const int fbB1 = (wn*64 + lq) * 64 + ((4 + lg) ^ lq7) * 8;

    floatx4 acc[4][4];
    #pragma unroll
    for (int i = 0; i < 4; ++i)
        #pragma unroll
        for (int j = 0; j < 4; ++j)
            acc[i][j] = (floatx4){0.f, 0.f, 0.f, 0.f};

#define GSTAGE_H1(KK_, BUF_) do {                                                              \
        gload_lds16(A  + (size_t)(row0 + arow[0]) * K + (KK_) + acol[0], &As[BUF_][(w*256 +   0) * 8]); \
        gload_lds16(A  + (size_t)(row0 + arow[1]) * K + (KK_) + acol[1], &As[BUF_][(w*256 +  64) * 8]); \
        gload_lds16(BT + (size_t)(col0 + brow[0]) * K + (KK_) + bcol[0], &Bs[BUF_][(w*128 +   0) * 8]); \
    } while (0)
#define GSTAGE_H2(KK_, BUF_) do {                                                              \
        gload_lds16(A  + (size_t)(row0 + arow[2]) * K + (KK_) + acol[2], &As[BUF_][(w*256 + 128) * 8]); \
        gload_lds16(A  + (size_t)(row0 + arow[3]) * K + (KK_) + acol[3], &As[BUF_][(w*256 + 192) * 8]); \
        gload_lds16(BT + (size_t)(col0 + brow[1]) * K + (KK_) + bcol[1], &Bs[BUF_][(w*128 +  64) * 8]); \
    } while (0)

    const int NKT = K >> 6;
    GSTAGE_H1(0, 0);  GSTAGE_H2(0, 0);
    GSTAGE_H1(64, 1); GSTAGE_H2(64, 1);

    int cur = 0;
    for (int kt = 0; kt < NKT; ++kt) {
        if (kt == NKT - 1) asm volatile("s_waitcnt vmcnt(0)" ::: "memory");
        else               asm volatile("s_waitcnt vmcnt(6)" ::: "memory");
        __builtin_amdgcn_s_barrier();
        __builtin_amdgcn_sched_barrier(0);

        int sb = cur + 2; if (sb >= 3) sb -= 3;
        const int kk2 = (kt + 2) << 6;
        const bool do_stage = (kt + 2 < NKT);

        {
            short8v af[4], bf[4];
            #pragma unroll
            for (int mi = 0; mi < 4; ++mi) af[mi] = *(const short8v*)(&As[cur][fbA0 + mi*1024]);
            #pragma unroll
            for (int ni = 0; ni < 4; ++ni) bf[ni] = *(const short8v*)(&Bs[cur][fbB0 + ni*1024]);
            if (do_stage) GSTAGE_H1(kk2, sb);
            __builtin_amdgcn_s_setprio(1);
            #pragma unroll
            for (int mi = 0; mi < 4; ++mi)
                #pragma unroll
                for (int ni = 0; ni < 4; ++ni)
                    acc[mi][ni] = __builtin_amdgcn_mfma_f32_16x16x32_bf16(af[mi], bf[ni], acc[mi][ni], 0, 0, 0);
            __builtin_amdgcn_s_setprio(0);
        }
        __builtin_amdgcn_s_barrier();
        {
            short8v af[4], bf[4];
            #pragma unroll
            for (int mi = 0; mi < 4; ++mi) af[mi] = *(const short8v*)(&As[cur][fbA1 + mi*1024]);
            #pragma unroll
            for (int ni = 0; ni < 4; ++ni) bf[ni] = *(const short8v*)(&Bs[cur][fbB1 + ni*1024]);
            if (do_stage) GSTAGE_H2(kk2, sb);
            __builtin_amdgcn_s_setprio(1);
            #pragma unroll
            for (int mi = 0; mi < 4; ++mi)
                #pragma unroll
                for (int ni = 0; ni < 4; ++ni)
                    acc[mi][ni] = __builtin_amdgcn_mfma_f32_16x16x32_bf16(af[mi], bf[ni], acc[mi][ni], 0, 0, 0);
            __builtin_amdgcn_s_setprio(0);
        }

        cur = (cur == 2) ? 0 : cur + 1;
    }
#undef GSTAGE_H1
#undef GSTAGE_H2

    if constexpr (FUSE_VT) {
        if (col0 >= 2*EMBED) {
            // ---- V third: d-major LDS bounce, all-vector traffic ----
            unsigned short* Tl = &As[0][0];     // need 128*264*2 = 67.6 KB <= 96 KB
            const int TR = 264;                 // halfword stride per d-column (+8 pad)
            __syncthreads();                    // all waves done reading As
            #pragma unroll
            for (int ni = 0; ni < 4; ++ni) {
                int cl = wn*64 + ni*16 + lq;    // 0..127 (d within block)
                float bv = bias[col0 + cl];
                #pragma unroll
                for (int mi = 0; mi < 4; ++mi) {
                    uint2 uu;
                    uu.x = cvt_pk_bf16(acc[mi][ni][0] + bv, acc[mi][ni][1] + bv);
                    uu.y = cvt_pk_bf16(acc[mi][ni][2] + bv, acc[mi][ni][3] + bv);
                    *(uint2*)(Tl + cl*TR + wm*64 + mi*16 + lg*4) = uu;
                }
            }
            __syncthreads();
            const int b_ = row0 >> 11;              // batch
            const int n0 = row0 & 2047;             // kv base within sequence
            const int h0 = (col0 - 2*EMBED) >> 6;   // first head in this block
            #pragma unroll
            for (int i = 0; i < 8; ++i) {
                int s = i * 512 + tid;              // 0..4095
                int cp = s & 7, t = (s >> 3) & 3, d = (s >> 5) & 63, hh = s >> 11;
                int c = cp ^ (d & 7);
                int base = (c >> 2) * 32 + (c & 3) * 4;
                int cl = hh*64 + d;
                uint2 lo = *(const uint2*)(Tl + cl*TR + t*64 + base);
                uint2 hi = *(const uint2*)(Tl + cl*TR + t*64 + base + 16);
                uint4v tv = (uint4v){ lo.x, lo.y, hi.x, hi.y };
                int bh = b_ * 16 + h0 + hh;
                *(short8v*)(vtout + ((size_t)bh * HDIM + d) * SEQ + n0 + t*64 + cp*8) =
                    __builtin_bit_cast(short8v, tv);
            }
            return;
        }
    }

    #pragma unroll
    for (int mi = 0; mi < 4; ++mi) {
        #pragma unroll
        for (int ni = 0; ni < 4; ++ni) {
            int col = col0 + wn*64 + ni*16 + lq;
            float bv = bias[col];
            #pragma unroll
            for (int r = 0; r < 4; ++r) {
                int row = row0 + wm*64 + mi*16 + lg*4 + r;
                float v = acc[mi][ni][r] + bv;
                if constexpr (SCALE_Q) { if (col < EMBED) v *= QSCALE; }
                if constexpr (OUT_BF16)
                    ((unsigned short*)Cout)[(size_t)row * N + col] = f2bf(v);
                else
                    ((float*)Cout)[(size_t)row * N + col] = v;
            }
        }
    }
}

// ---------------------------------------------------------------------------
// MFMA flash attention (final form, ~72 us, issue-saturated: MfmaUtil +
// VALUBusy ~ 88%): 8 waves / 512 threads, QBLK=256, swapped QK^T,
// pi-permuted PV, no-max softmax, ones-MFMA lsum, XCD remap, paired 2x2
// K/V buffers (64 KB), one vmcnt(0)+s_barrier per 2-tile epoch,
// wave-staggered tile order.
// ---------------------------------------------------------------------------
__global__ __launch_bounds__(512) void attn_mfma(const unsigned short* __restrict__ qkvb,
                                                 const unsigned short* __restrict__ vt,
                                                 unsigned short* __restrict__ attout) {
    const int flat = blockIdx.x;          // 0..511
    const int idx = flat >> 3;            // 0..63
    const int bh = (flat & 7) * 8 + (idx >> 3);
    const int qb = idx & 7;
    const int b = bh >> 4, h = bh & 15;
    const int tid = threadIdx.x;
    const int lane = tid & 63;
    const int w = tid >> 6;               // 0..7
    const int lq = lane & 15, lg = lane >> 4;
    const int rb = lq & 7;

    __shared__ __align__(16) unsigned short Ks[2][2][64 * 64];   // 32 KB
    __shared__ __align__(16) unsigned short Vs[2][2][64 * 64];   // 32 KB

    short8v qf[2][2];
    const unsigned short* qbase = qkvb + (size_t)(b*SEQ + qb*256 + w*32) * QKV_LD + h*HDIM;
    #pragma unroll
    for (int m = 0; m < 2; ++m)
        #pragma unroll
        for (int ks = 0; ks < 2; ++ks)
            qf[m][ks] = *(const short8v*)(qbase + (size_t)(m*16 + lq) * QKV_LD + ks*32 + lg*8);

    floatx4 o[2][4];
    #pragma unroll
    for (int m = 0; m < 2; ++m)
        #pragma unroll
        for (int dt = 0; dt < 4; ++dt)
            o[m][dt] = (floatx4){0.f, 0.f, 0.f, 0.f};
    floatx4 lacc[2];
    lacc[0] = (floatx4){0.f, 0.f, 0.f, 0.f};
    lacc[1] = (floatx4){0.f, 0.f, 0.f, 0.f};

    const uint4v onesu = (uint4v){0x3F803F80u, 0x3F803F80u, 0x3F803F80u, 0x3F803F80u};
    const short8v onesf = __builtin_bit_cast(short8v, onesu);

    const unsigned short* kbase = qkvb + (size_t)(b*SEQ) * QKV_LD + EMBED + h*HDIM;
    const unsigned short* vbase = vt + (size_t)bh * HDIM * SEQ;

    const int r0 = tid >> 3;
    const int ck0 = (tid & 7) ^ (r0 & 7);
    const int cv0 = tid & 7;

    const int cA = (lg ^ rb) * 8, cB = ((lg ^ rb) ^ 4) * 8;
    const int fbA = lq * 64 + cA, fbB = lq * 64 + cB;
    const int sw0 = w & 1;                 // this wave's first sub-tile

#define STAGE(T_, PP_, SS_) do {                                                   \
        const unsigned short* kb_ = kbase + (size_t)(T_) * 64 * QKV_LD;            \
        const unsigned short* vb_ = vbase + (T_) * 64;                             \
        gload_lds16(kb_ + (size_t)r0 * QKV_LD + ck0*8, &Ks[PP_][SS_][w*512]);      \
        gload_lds16(vb_ + (size_t)r0 * SEQ + cv0*8,    &Vs[PP_][SS_][w*512]);      \
    } while (0)

#define ACOMP(PP_, SS_) do {                                                                   \
        const unsigned short* K0 = &Ks[PP_][SS_][fbA];                                         \
        const unsigned short* K1 = &Ks[PP_][SS_][fbB];                                         \
        const unsigned short* V0 = &Vs[PP_][SS_][fbA];                                         \
        const unsigned short* V1 = &Vs[PP_][SS_][fbB];                                         \
        floatx4 sacc[2][4];                                                                    \
        _Pragma("unroll")                                                                      \
        for (int n = 0; n < 4; ++n) {                                                          \
            short8v kf0 = *(const short8v*)(K0 + n * 1024);                                    \
            short8v kf1 = *(const short8v*)(K1 + n * 1024);                                    \
            __builtin_amdgcn_s_setprio(1);                                                     \
            _Pragma("unroll")                                                                  \
            for (int m = 0; m < 2; ++m) {                                                      \
                floatx4 z = (floatx4){0.f, 0.f, 0.f, 0.f};                                     \
                z = __builtin_amdgcn_mfma_f32_16x16x32_bf16(kf0, qf[m][0], z, 0, 0, 0);        \
                sacc[m][n] = __builtin_amdgcn_mfma_f32_16x16x32_bf16(kf1, qf[m][1], z, 0, 0, 0); \
            }                                                                                  \
            __builtin_amdgcn_s_setprio(0);                                                     \
        }                                                                                      \
        uint4v afu[2][2];                                                                      \
        _Pragma("unroll")                                                                      \
        for (int m = 0; m < 2; ++m) {                                                          \
            unsigned int pk[4][2];                                                             \
            _Pragma("unroll")                                                                  \
            for (int n = 0; n < 4; ++n) {                                                      \
                float p0 = fast_exp2(sacc[m][n][0]);                                           \
                float p1 = fast_exp2(sacc[m][n][1]);                                           \
                float p2 = fast_exp2(sacc[m][n][2]);                                           \
                float p3 = fast_exp2(sacc[m][n][3]);                                           \
                pk[n][0] = cvt_pk_bf16(p0, p1);                                                \
                pk[n][1] = cvt_pk_bf16(p2, p3);                                                \
            }                                                                                  \
            afu[m][0] = (uint4v){ pk[0][0], pk[0][1], pk[1][0], pk[1][1] };                    \
            afu[m][1] = (uint4v){ pk[2][0], pk[2][1], pk[3][0], pk[3][1] };                    \
        }                                                                                      \
        __builtin_amdgcn_s_setprio(1);                                                         \
        _Pragma("unroll")                                                                      \
        for (int m = 0; m < 2; ++m) {                                                          \
            lacc[m] = __builtin_amdgcn_mfma_f32_16x16x32_bf16(                                 \
                __builtin_bit_cast(short8v, afu[m][0]), onesf, lacc[m], 0, 0, 0);              \
            lacc[m] = __builtin_amdgcn_mfma_f32_16x16x32_bf16(                                 \
                __builtin_bit_cast(short8v, afu[m][1]), onesf, lacc[m], 0, 0, 0);              \
        }                                                                                      \
        __builtin_amdgcn_s_setprio(0);                                                         \
        _Pragma("unroll")                                                                      \
        for (int dt = 0; dt < 4; ++dt) {                                                       \
            short8v vf0 = *(const short8v*)(V0 + dt * 1024);                                   \
            short8v vf1 = *(const short8v*)(V1 + dt * 1024);                                   \
            __builtin_amdgcn_s_setprio(1);                                                     \
            _Pragma("unroll")                                                                  \
            for (int m = 0; m < 2; ++m) {                                                      \
                o[m][dt] = __builtin_amdgcn_mfma_f32_16x16x32_bf16(                            \
                    __builtin_bit_cast(short8v, afu[m][0]), vf0, o[m][dt], 0, 0, 0);           \
                o[m][dt] = __builtin_amdgcn_mfma_f32_16x16x32_bf16(                            \
                    __builtin_bit_cast(short8v, afu[m][1]), vf1, o[m][dt], 0, 0, 0);           \
            }                                                                                  \
            __builtin_amdgcn_s_setprio(0);                                                     \
        }                                                                                      \
    } while (0)

    const int NT = SEQ / 64;   // 32
    STAGE(0, 0, 0);
    STAGE(1, 0, 1);

    for (int kt = 0; kt < NT; kt += 2) {
        const int p = (kt >> 1) & 1;
        asm volatile("s_waitcnt vmcnt(0)" ::: "memory");
        __builtin_amdgcn_s_barrier();
        __builtin_amdgcn_sched_barrier(0);

        if (kt + 2 < NT) {
            STAGE(kt + 2, p ^ 1, 0);
            STAGE(kt + 3, p ^ 1, 1);
        }

        ACOMP(p, sw0);
        ACOMP(p, sw0 ^ 1);
    }
#undef ACOMP
#undef STAGE

    // ---- epilogue: lacc rows (lg*4+r) match o rows exactly — no shuffles ----
    #pragma unroll
    for (int m = 0; m < 2; ++m) {
        #pragma unroll
        for (int dt = 0; dt < 4; ++dt) {
            #pragma unroll
            for (int r = 0; r < 4; ++r) {
                float v = o[m][dt][r] / lacc[m][r];
                int row = qb*256 + w*32 + m*16 + lg*4 + r;
                int col = h*HDIM + dt*16 + lq;
                attout[(size_t)(b*SEQ + row) * EMBED + col] = f2bf(v);
            }
        }
    }
}

// ---------------------------------------------------------------------------
extern "C" void kernel_launch(void* const* d_in, const int* in_sizes, int n_in,
                              void* d_out, int out_size, void* d_ws, size_t ws_size,
                              hipStream_t stream) {
    const float* x      = (const float*)d_in[0];
    const float* W_qkv  = (const float*)d_in[1];
    const float* b_qkv  = (const float*)d_in[2];
    const float* W_proj = (const float*)d_in[3];
    const float* b_proj = (const float*)d_in[4];
    float* out = (float*)d_out;

    const int M = BATCH * SEQ;   // 8192

    char* ws = (char*)d_ws;
    unsigned short* x_b    = (unsigned short*)(ws);                 // 16 MB
    unsigned short* wqkvT  = (unsigned short*)(ws + 16777216);      // 6 MB
    unsigned short* wprojT = (unsigned short*)(ws + 23068672);      // 2 MB
    unsigned short* qkv_b  = (unsigned short*)(ws + 25165824);      // 48 MB
    unsigned short* vt_b   = (unsigned short*)(ws + 75497472);      // 16 MB
    unsigned short* att_b  = (unsigned short*)(ws + 92274688);      // 16 MB

    // one fused prep launch: cast(8192) + tqkv(768) + tproj(256) = 9216 blocks
    prep_kernel<<<dim3(9216), 256, 0, stream>>>(x, x_b, W_qkv, wqkvT, W_proj, wprojT);

    // QKV: grid 32*24 = 768 blocks; V third written directly to vt_b
    gemm_bf16<true, true, true><<<dim3(768), 512, 0, stream>>>(
        x_b, wqkvT, b_qkv, qkv_b, vt_b, M, QKV_LD, EMBED);

    // attn: grid 512 (QBLK=256)
    attn_mfma<<<dim3(512), dim3(512), 0, stream>>>(qkv_b, vt_b, att_b);

    // proj: grid 32*8 = 256 blocks
    gemm_bf16<false, false, false><<<dim3(256), 512, 0, stream>>>(
        att_b, wprojT, b_proj, out, nullptr, M, EMBED, EMBED);
}